// Round 2
// 928.152 us; speedup vs baseline: 1.0345x; 1.0345x over previous
//
#include <hip/hip_runtime.h>
#include <hip/hip_bf16.h>

// Swin block: B=64, H=W=56, C=128, WS=7, SHIFT=3, NH=4, hd=32, hidden=512
// Tokens: 200704. Windows: 4096, L=49. fp32 I/O.
// Planar bf16 hi/lo activation/weight planes everywhere (numerically identical
// to fp32-store + split-at-stage), weights pre-split once, 128x128 GEMM tiles
// with register prefetch, QKV->attn link in pure bf16 with Q-scale folded into
// pre-split weights. Removes split2 from all GEMM hot loops and most redundant
// A re-reads.
// ws layout: [0,64K) btab | [64K, 64K+768K) weight planes | bufA planes | bufB planes.
// (Resubmit: round-1 bench died on container acquire, not kernel.)

#define NWIN 4096
#define STR 40   // GEMM LDS stride (shorts); 80 B rows -> worst 2-way bank alias = free

typedef __attribute__((ext_vector_type(8))) short s8v;
typedef __attribute__((ext_vector_type(4))) float f4v;

__device__ __forceinline__ void split2(float v, unsigned short& h, unsigned short& l) {
    unsigned int b = __float_as_uint(v);
    h = (unsigned short)(b >> 16);                       // truncated hi
    float hf = __uint_as_float(b & 0xFFFF0000u);
    __hip_bfloat16 lo = __float2bfloat16(v - hf);        // exact residual, RNE
    l = *reinterpret_cast<unsigned short*>(&lo);
}
__device__ __forceinline__ unsigned short bfr(float v) {  // RNE bf16 bits
    __hip_bfloat16 h = __float2bfloat16(v);
    return *reinterpret_cast<unsigned short*>(&h);
}
__device__ __forceinline__ float b2f(unsigned short u) {
    return __uint_as_float((unsigned int)u << 16);
}

// ---------------- weight pre-split: fp32 -> planar bf16 hi/lo (once) ----------------
// plane offsets (shorts): qkvWh 0, qkvWl 49152, outWh 98304, outWl 114688,
//                         w1h 131072, w1l 196608, w2h 262144, w2l 327680
__global__ __launch_bounds__(256) void presplit_kernel(
    const float* __restrict__ qkvw, const float* __restrict__ outw,
    const float* __restrict__ w1, const float* __restrict__ w2,
    unsigned short* __restrict__ P)
{
    int i = blockIdx.x * 256 + threadIdx.x;
    float v; unsigned short* ph; unsigned short* pl;
    if (i < 49152) {
        v = qkvw[i];
        if (i < 16384) v *= 0.17677669529663687f;   // fold 1/sqrt(32) into Q rows
        ph = P + i; pl = P + 49152 + i;
    } else if (i < 65536) {
        int j = i - 49152; v = outw[j];
        ph = P + 98304 + j; pl = P + 114688 + j;
    } else if (i < 131072) {
        int j = i - 65536; v = w1[j];
        ph = P + 131072 + j; pl = P + 196608 + j;
    } else if (i < 196608) {
        int j = i - 131072; v = w2[j];
        ph = P + 262144 + j; pl = P + 327680 + j;
    } else return;
    unsigned short h, l; split2(v, h, l);
    *ph = h; *pl = l;
}

// ---------------- LN: fp32 (mode 0, shift-gather) or hi/lo planes (mode 1) in; planes out ----------------
__global__ __launch_bounds__(256) void ln_kernel(
    const float* __restrict__ inF,
    const unsigned short* __restrict__ inH, const unsigned short* __restrict__ inL,
    const float* __restrict__ g, const float* __restrict__ bta,
    unsigned short* __restrict__ outH, unsigned short* __restrict__ outL,
    int mode, int tbase)
{
    int tid = threadIdx.x;
    int wave = tid >> 6, lane = tid & 63;
    int local = blockIdx.x * 4 + wave;
    float v0, v1;
    if (mode == 0) {
        int t = tbase + local;
        int n = t / 49, l = t - n * 49;
        int b = n >> 6, wh = (n >> 3) & 7, ww = n & 7;
        int i = l / 7, j = l - i * 7;
        int hh = wh * 7 + i, wimg = ww * 7 + j;
        int sh = (hh + 53) % 56, sw = (wimg + 53) % 56;
        const float* ip = inF + (size_t)((b * 56 + sh) * 56 + sw) * 128;
        v0 = ip[lane]; v1 = ip[lane + 64];
    } else {
        size_t o = (size_t)local * 128;
        v0 = b2f(inH[o + lane])      + b2f(inL[o + lane]);
        v1 = b2f(inH[o + lane + 64]) + b2f(inL[o + lane + 64]);
    }
    float s = v0 + v1, sq = v0 * v0 + v1 * v1;
    #pragma unroll
    for (int off = 32; off > 0; off >>= 1) { s += __shfl_xor(s, off); sq += __shfl_xor(sq, off); }
    float mean = s * (1.0f / 128.0f);
    float var  = sq * (1.0f / 128.0f) - mean * mean;
    float rstd = rsqrtf(var + 1e-5f);
    float r0 = (v0 - mean) * rstd * g[lane]      + bta[lane];
    float r1 = (v1 - mean) * rstd * g[lane + 64] + bta[lane + 64];
    unsigned short h0, l0, h1, l1;
    split2(r0, h0, l0); split2(r1, h1, l1);
    size_t o = (size_t)local * 128;
    outH[o + lane] = h0; outH[o + lane + 64] = h1;
    outL[o + lane] = l0; outL[o + lane + 64] = l1;
}

// ---------------- GEMM: planar hi/lo in, 128x128 tile, 3-term split MFMA ----------------
// mode: 0 = hi/lo planes out; 1 = GELU + planes out; 2 = bf16 out (qkv; bias cols<128
//        pre-scaled by 1/sqrt(32)); 3 = fp32 scatter-remap out (fc2 -> y)
__global__ __launch_bounds__(256, 2) void gemm_mfma(
    const unsigned short* __restrict__ Agh, const unsigned short* __restrict__ Agl,
    const unsigned short* __restrict__ Wgh, const unsigned short* __restrict__ Wgl,
    const float* __restrict__ bias,
    float* __restrict__ OutF, unsigned short* __restrict__ OutH, unsigned short* __restrict__ OutL,
    int M, int N, int K, int mode, int tbase)
{
    __shared__ __align__(16) unsigned short Ah[128 * STR];
    __shared__ __align__(16) unsigned short Al[128 * STR];
    __shared__ __align__(16) unsigned short Wh[128 * STR];
    __shared__ __align__(16) unsigned short Wl[128 * STR];
    int tid = threadIdx.x;
    int wv = tid >> 6, ln = tid & 63;
    int wm = wv & 1, wn = wv >> 1;
    int fm = ln & 15, fq = ln >> 4;
    int m0 = blockIdx.y * 128, n0 = blockIdx.x * 128;
    int sr = tid >> 1, sh = (tid & 1) * 16;
    int arow = m0 + sr; if (arow >= M) arow = M - 1;
    const unsigned short* pAh = Agh + (size_t)arow * K + sh;
    const unsigned short* pAl = Agl + (size_t)arow * K + sh;
    const unsigned short* pWh = Wgh + (size_t)(n0 + sr) * K + sh;
    const unsigned short* pWl = Wgl + (size_t)(n0 + sr) * K + sh;
    int so = sr * STR + sh;

    f4v acc[4][4] = {};
    s8v ra0, ra1, rb0, rb1, rc0, rc1, rd0, rd1;
    #define LOADK(k0) do { \
        ra0 = *reinterpret_cast<const s8v*>(pAh + (k0)); ra1 = *reinterpret_cast<const s8v*>(pAh + (k0) + 8); \
        rb0 = *reinterpret_cast<const s8v*>(pAl + (k0)); rb1 = *reinterpret_cast<const s8v*>(pAl + (k0) + 8); \
        rc0 = *reinterpret_cast<const s8v*>(pWh + (k0)); rc1 = *reinterpret_cast<const s8v*>(pWh + (k0) + 8); \
        rd0 = *reinterpret_cast<const s8v*>(pWl + (k0)); rd1 = *reinterpret_cast<const s8v*>(pWl + (k0) + 8); } while (0)
    LOADK(0);
    for (int k0 = 0; k0 < K; k0 += 32) {
        *reinterpret_cast<s8v*>(&Ah[so]) = ra0; *reinterpret_cast<s8v*>(&Ah[so + 8]) = ra1;
        *reinterpret_cast<s8v*>(&Al[so]) = rb0; *reinterpret_cast<s8v*>(&Al[so + 8]) = rb1;
        *reinterpret_cast<s8v*>(&Wh[so]) = rc0; *reinterpret_cast<s8v*>(&Wh[so + 8]) = rc1;
        *reinterpret_cast<s8v*>(&Wl[so]) = rd0; *reinterpret_cast<s8v*>(&Wl[so + 8]) = rd1;
        __syncthreads();
        if (k0 + 32 < K) LOADK(k0 + 32);           // prefetch next k-step (issue early)
        s8v fah[4], fal[4], fbh[4], fbl[4];
        #pragma unroll
        for (int t = 0; t < 4; ++t) {
            int ao = (wm * 64 + t * 16 + fm) * STR + fq * 8;
            fah[t] = *reinterpret_cast<const s8v*>(&Ah[ao]);
            fal[t] = *reinterpret_cast<const s8v*>(&Al[ao]);
            int bo = (wn * 64 + t * 16 + fm) * STR + fq * 8;
            fbh[t] = *reinterpret_cast<const s8v*>(&Wh[bo]);
            fbl[t] = *reinterpret_cast<const s8v*>(&Wl[bo]);
        }
        #pragma unroll
        for (int mt = 0; mt < 4; ++mt)
            #pragma unroll
            for (int nt = 0; nt < 4; ++nt) {
                acc[mt][nt] = __builtin_amdgcn_mfma_f32_16x16x32_bf16(fah[mt], fbh[nt], acc[mt][nt], 0, 0, 0);
                acc[mt][nt] = __builtin_amdgcn_mfma_f32_16x16x32_bf16(fah[mt], fbl[nt], acc[mt][nt], 0, 0, 0);
                acc[mt][nt] = __builtin_amdgcn_mfma_f32_16x16x32_bf16(fal[mt], fbh[nt], acc[mt][nt], 0, 0, 0);
            }
        __syncthreads();
    }
    #undef LOADK

    #pragma unroll
    for (int mt = 0; mt < 4; ++mt)
        #pragma unroll
        for (int nt = 0; nt < 4; ++nt) {
            int col = n0 + wn * 64 + nt * 16 + fm;
            float bv = bias[col];
            if (mode == 2 && col < 128) bv *= 0.17677669529663687f;
            #pragma unroll
            for (int r = 0; r < 4; ++r) {
                int m = m0 + wm * 64 + mt * 16 + fq * 4 + r;
                if (m >= M) continue;
                float v = acc[mt][nt][r] + bv;
                if (mode == 1) v = 0.5f * v * (1.0f + erff(v * 0.70710678118654752f));
                if (mode == 3) {
                    int t = tbase + m;
                    int n = t / 49, l = t - n * 49;
                    int b = n >> 6, wh_ = (n >> 3) & 7, ww = n & 7;
                    int i = l / 7, j = l - i * 7;
                    size_t orow = (size_t)((b * 56 + wh_ * 7 + i) * 56 + ww * 7 + j);
                    OutF[orow * N + col] = v;
                } else if (mode == 2) {
                    OutH[(size_t)m * N + col] = bfr(v);
                } else {
                    unsigned short hh, ll; split2(v, hh, ll);
                    OutH[(size_t)m * N + col] = hh;
                    OutL[(size_t)m * N + col] = ll;
                }
            }
        }
}

// ---------------- bias table in MFMA C-layout: [4][64 lanes][16 (mt,nt)][4 r] ----------------
__global__ void bias_tab_kernel(const float* __restrict__ pe, float* __restrict__ tab) {
    int t = threadIdx.x;          // 256 = 4 heads x 64 lanes
    int h = t >> 6, ln = t & 63;
    int g = ln >> 4, c = ln & 15;
    for (int mt = 0; mt < 4; ++mt)
        for (int nt = 0; nt < 4; ++nt)
            for (int r = 0; r < 4; ++r) {
                int l1 = mt * 16 + g * 4 + r, l2 = nt * 16 + c;
                float b = 0.f;
                if (l1 < 49 && l2 < 49) {
                    int i1 = l1 / 7, j1 = l1 % 7, i2 = l2 / 7, j2 = l2 % 7;
                    b = pe[h * 169 + (i1 - i2 + 6) * 13 + (j1 - j2 + 6)];
                }
                tab[((h * 64 + ln) * 16 + mt * 4 + nt) * 4 + r] = b;
            }
}

// ---------------- MFMA attention: one block per window, wave = head ----------------
// Input: qkv bf16 [wpc,49,384] (Q pre-scaled). Output: hi/lo planes [wpc,49,128].
// Per-head LDS (shorts): Q[64*40]  K[64*40]  V^T[32*72]; P[64*72] aliases Q+K.
#define HB 7424   // per-head shorts: 2560 + 2560 + 2304
__global__ __launch_bounds__(256) void attn_mfma(
    const unsigned short* __restrict__ qkv,
    const float* __restrict__ btab,
    unsigned short* __restrict__ oH, unsigned short* __restrict__ oL)
{
    __shared__ __align__(16) unsigned short lds[4 * HB];
    int tid = threadIdx.x;
    int win = blockIdx.x;
    const unsigned short* src = qkv + (size_t)win * 49 * 384;

    // zero V^T pad cols l2=49..63 (4 heads x 32 d x 15)
    for (int i = tid; i < 1920; i += 256) {
        int hh = i / 480, rem = i % 480, d = rem / 15, l2 = 49 + rem % 15;
        lds[hh * HB + 5120 + d * 72 + l2] = 0;
    }
    // stage QKV bf16 -> LDS (Q already scaled)
    for (int idx = tid; idx < 2352; idx += 256) {
        int l2 = idx / 48, c8 = idx - l2 * 48;
        int d8 = c8 * 8;
        s8v v8 = *reinterpret_cast<const s8v*>(src + (size_t)l2 * 384 + d8);
        int sec = d8 >> 7, dd = d8 & 127, hh = dd >> 5, kk = dd & 31;
        int base = hh * HB;
        if (sec <= 1) {
            *reinterpret_cast<s8v*>(&lds[base + sec * 2560 + l2 * 40 + kk]) = v8;
        } else {
            #pragma unroll
            for (int i = 0; i < 8; ++i)
                lds[base + 5120 + (kk + i) * 72 + l2] = (unsigned short)v8[i];
        }
    }
    __syncthreads();

    int h = tid >> 6, ln = tid & 63;
    int fm = ln & 15, fq = ln >> 4;
    int base = h * HB;

    // S = Q @ K^T  (+ bias from table)
    s8v Qf[4], Kf[4];
    #pragma unroll
    for (int t = 0; t < 4; ++t) {
        Qf[t] = *reinterpret_cast<const s8v*>(&lds[base + (t * 16 + fm) * 40 + fq * 8]);
        Kf[t] = *reinterpret_cast<const s8v*>(&lds[base + 2560 + (t * 16 + fm) * 40 + fq * 8]);
    }
    f4v S[4][4] = {};
    #pragma unroll
    for (int mt = 0; mt < 4; ++mt)
        #pragma unroll
        for (int nt = 0; nt < 4; ++nt)
            S[mt][nt] = __builtin_amdgcn_mfma_f32_16x16x32_bf16(Qf[mt], Kf[nt], S[mt][nt], 0, 0, 0);
    #pragma unroll
    for (int mt = 0; mt < 4; ++mt)
        #pragma unroll
        for (int nt = 0; nt < 4; ++nt)
            S[mt][nt] += *reinterpret_cast<const f4v*>(&btab[((h * 64 + ln) * 16 + mt * 4 + nt) * 4]);

    // in-register softmax per row (rows live in 16-lane shuffle groups); P -> LDS (aliases Q+K)
    float rcp[16];
    #pragma unroll
    for (int mt = 0; mt < 4; ++mt) {
        #pragma unroll
        for (int r = 0; r < 4; ++r) {
            float v0 = S[mt][0][r], v1 = S[mt][1][r], v2 = S[mt][2][r], v3 = S[mt][3][r];
            if (fm != 0) v3 = -1e30f;                       // cols 49..63 masked
            float mx = fmaxf(fmaxf(v0, v1), fmaxf(v2, v3));
            #pragma unroll
            for (int off = 1; off < 16; off <<= 1) mx = fmaxf(mx, __shfl_xor(mx, off));
            float e0 = __expf(v0 - mx), e1 = __expf(v1 - mx);
            float e2 = __expf(v2 - mx), e3 = __expf(v3 - mx); // masked -> 0
            float sm = e0 + e1 + e2 + e3;
            #pragma unroll
            for (int off = 1; off < 16; off <<= 1) sm += __shfl_xor(sm, off);
            rcp[mt * 4 + r] = 1.0f / sm;
            int row = mt * 16 + fq * 4 + r;
            lds[base + row * 72 + 0 * 16 + fm]  = bfr(e0);
            lds[base + row * 72 + 1 * 16 + fm]  = bfr(e1);
            lds[base + row * 72 + 2 * 16 + fm]  = bfr(e2);
            lds[base + row * 72 + 3 * 16 + fm]  = bfr(e3);
        }
    }

    // O = P @ V   (V^T staged as B operand; k = l2, two k-steps)
    f4v O[4][2] = {};
    #pragma unroll
    for (int kt = 0; kt < 2; ++kt) {
        s8v Pf[4], Vf[2];
        #pragma unroll
        for (int mt = 0; mt < 4; ++mt)
            Pf[mt] = *reinterpret_cast<const s8v*>(&lds[base + (mt * 16 + fm) * 72 + kt * 32 + fq * 8]);
        #pragma unroll
        for (int nt = 0; nt < 2; ++nt)
            Vf[nt] = *reinterpret_cast<const s8v*>(&lds[base + 5120 + (nt * 16 + fm) * 72 + kt * 32 + fq * 8]);
        #pragma unroll
        for (int mt = 0; mt < 4; ++mt)
            #pragma unroll
            for (int nt = 0; nt < 2; ++nt)
                O[mt][nt] = __builtin_amdgcn_mfma_f32_16x16x32_bf16(Pf[mt], Vf[nt], O[mt][nt], 0, 0, 0);
    }

    size_t ob = (size_t)win * 49 * 128 + h * 32;
    #pragma unroll
    for (int mt = 0; mt < 4; ++mt)
        #pragma unroll
        for (int r = 0; r < 4; ++r) {
            int row = mt * 16 + fq * 4 + r;
            if (row < 49) {
                float sc = rcp[mt * 4 + r];
                #pragma unroll
                for (int nt = 0; nt < 2; ++nt) {
                    unsigned short hh, ll;
                    split2(O[mt][nt][r] * sc, hh, ll);
                    oH[ob + (size_t)row * 128 + nt * 16 + fm] = hh;
                    oL[ob + (size_t)row * 128 + nt * 16 + fm] = ll;
                }
            }
        }
}

extern "C" void kernel_launch(void* const* d_in, const int* in_sizes, int n_in,
                              void* d_out, int out_size, void* d_ws, size_t ws_size,
                              hipStream_t stream) {
    const float* x    = (const float*)d_in[0];
    const float* n1g  = (const float*)d_in[1];
    const float* n1b  = (const float*)d_in[2];
    const float* qkvw = (const float*)d_in[3];
    const float* qkvb = (const float*)d_in[4];
    const float* outw = (const float*)d_in[5];
    const float* outb = (const float*)d_in[6];
    const float* pe   = (const float*)d_in[7];
    const float* n2g  = (const float*)d_in[8];
    const float* n2b  = (const float*)d_in[9];
    const float* w1   = (const float*)d_in[10];
    const float* b1   = (const float*)d_in[11];
    const float* w2   = (const float*)d_in[12];
    const float* b2   = (const float*)d_in[13];
    float* y = (float*)d_out;

    // fixed overhead: 64 KB btab + 768 KB weight planes = 851968 B
    size_t wpc = NWIN;
    while (wpc > 8 && 851968 + wpc * 49 * 2560 > ws_size) wpc >>= 1;
    const int nchunks = (int)(NWIN / wpc);
    const size_t rows = wpc * 49;

    char* ws = (char*)d_ws;
    float* btab = (float*)ws;                                    // 64 KB
    unsigned short* wpl = (unsigned short*)(ws + 65536);         // 786432 B of planes
    unsigned short* bufAh = (unsigned short*)(ws + 851968);      // rows*128 shorts
    unsigned short* bufAl = bufAh + rows * 128;                  // rows*128 shorts
    unsigned short* bufBh = bufAl + rows * 128;                  // rows*512 shorts
    unsigned short* bufBl = bufBh + rows * 512;                  // rows*512 shorts
    const int gy = (int)((rows + 127) / 128);

    presplit_kernel<<<768, 256, 0, stream>>>(qkvw, outw, w1, w2, wpl);
    bias_tab_kernel<<<1, 256, 0, stream>>>(pe, btab);

    for (int c = 0; c < nchunks; ++c) {
        int tbase = (int)(c * wpc * 49);
        ln_kernel<<<(int)(rows / 4), 256, 0, stream>>>(
            x, nullptr, nullptr, n1g, n1b, bufAh, bufAl, 0, tbase);
        gemm_mfma<<<dim3(3, gy), 256, 0, stream>>>(
            bufAh, bufAl, wpl, wpl + 49152, qkvb,
            nullptr, bufBh, nullptr, (int)rows, 384, 128, 2, 0);
        attn_mfma<<<(int)wpc, 256, 0, stream>>>(bufBh, btab, bufAh, bufAl);
        gemm_mfma<<<dim3(1, gy), 256, 0, stream>>>(
            bufAh, bufAl, wpl + 98304, wpl + 114688, outb,
            nullptr, bufBh, bufBl, (int)rows, 128, 128, 0, 0);
        ln_kernel<<<(int)(rows / 4), 256, 0, stream>>>(
            nullptr, bufBh, bufBl, n2g, n2b, bufAh, bufAl, 1, 0);
        gemm_mfma<<<dim3(4, gy), 256, 0, stream>>>(
            bufAh, bufAl, wpl + 131072, wpl + 196608, b1,
            nullptr, bufBh, bufBl, (int)rows, 512, 128, 1, 0);
        gemm_mfma<<<dim3(1, gy), 256, 0, stream>>>(
            bufBh, bufBl, wpl + 262144, wpl + 327680, b2,
            y, nullptr, nullptr, (int)rows, 128, 512, 3, tbase);
    }
}

// Round 3
// 739.308 us; speedup vs baseline: 1.2988x; 1.2554x over previous
//
#include <hip/hip_runtime.h>
#include <hip/hip_bf16.h>

// Swin block: B=64, H=W=56, C=128, WS=7, SHIFT=3, NH=4, hd=32, hidden=512
// Round 3: back to 64x64 GEMM tiles (occupancy ~6 blocks/CU vs 2 at 128x128),
// planar staging kept (no split2 in hot loops), and all intermediate links
// except LN1-out switched to single-plane bf16 (attn-out, proj-out, LN2-out,
// hidden). A-operand single-plane -> 2-term MFMA (A*Wh + A*Wl); weights stay
// hi/lo pre-split. Error budget: adds <=1.5e-4 in quadrature to the existing
// 2e-3 (bf16 q,k rounding) -> absmax unchanged.
// ws: [0,64K) btab | [64K,832K) weight planes | Ah | Al | Bh (rows x 1536 B).

#define NWIN 4096
#define STR 40   // GEMM LDS stride (shorts); 80 B rows

typedef __attribute__((ext_vector_type(8))) short s8v;
typedef __attribute__((ext_vector_type(4))) float f4v;

__device__ __forceinline__ void split2(float v, unsigned short& h, unsigned short& l) {
    unsigned int b = __float_as_uint(v);
    h = (unsigned short)(b >> 16);                       // truncated hi
    float hf = __uint_as_float(b & 0xFFFF0000u);
    __hip_bfloat16 lo = __float2bfloat16(v - hf);        // exact residual, RNE
    l = *reinterpret_cast<unsigned short*>(&lo);
}
__device__ __forceinline__ unsigned short bfr(float v) {  // RNE bf16 bits
    __hip_bfloat16 h = __float2bfloat16(v);
    return *reinterpret_cast<unsigned short*>(&h);
}
__device__ __forceinline__ float b2f(unsigned short u) {
    return __uint_as_float((unsigned int)u << 16);
}

// ---------------- weight pre-split: fp32 -> planar bf16 hi/lo (once) ----------------
// plane offsets (shorts): qkvWh 0, qkvWl 49152, outWh 98304, outWl 114688,
//                         w1h 131072, w1l 196608, w2h 262144, w2l 327680
__global__ __launch_bounds__(256) void presplit_kernel(
    const float* __restrict__ qkvw, const float* __restrict__ outw,
    const float* __restrict__ w1, const float* __restrict__ w2,
    unsigned short* __restrict__ P)
{
    int i = blockIdx.x * 256 + threadIdx.x;
    float v; unsigned short* ph; unsigned short* pl;
    if (i < 49152) {
        v = qkvw[i];
        if (i < 16384) v *= 0.17677669529663687f;   // fold 1/sqrt(32) into Q rows
        ph = P + i; pl = P + 49152 + i;
    } else if (i < 65536) {
        int j = i - 49152; v = outw[j];
        ph = P + 98304 + j; pl = P + 114688 + j;
    } else if (i < 131072) {
        int j = i - 65536; v = w1[j];
        ph = P + 131072 + j; pl = P + 196608 + j;
    } else if (i < 196608) {
        int j = i - 131072; v = w2[j];
        ph = P + 262144 + j; pl = P + 327680 + j;
    } else return;
    unsigned short h, l; split2(v, h, l);
    *ph = h; *pl = l;
}

// ---------------- LN ----------------
// mode 0: fp32 shift-gather in -> hi/lo planes out (LN1)
// mode 1: bf16 plane in -> bf16 plane out (LN2)
__global__ __launch_bounds__(256) void ln_kernel(
    const float* __restrict__ inF, const unsigned short* __restrict__ inH,
    const float* __restrict__ g, const float* __restrict__ bta,
    unsigned short* __restrict__ outH, unsigned short* __restrict__ outL,
    int mode, int tbase)
{
    int tid = threadIdx.x;
    int wave = tid >> 6, lane = tid & 63;
    int local = blockIdx.x * 4 + wave;
    float v0, v1;
    if (mode == 0) {
        int t = tbase + local;
        int n = t / 49, l = t - n * 49;
        int b = n >> 6, wh = (n >> 3) & 7, ww = n & 7;
        int i = l / 7, j = l - i * 7;
        int hh = wh * 7 + i, wimg = ww * 7 + j;
        int sh = (hh + 53) % 56, sw = (wimg + 53) % 56;
        const float* ip = inF + (size_t)((b * 56 + sh) * 56 + sw) * 128;
        v0 = ip[lane]; v1 = ip[lane + 64];
    } else {
        size_t o = (size_t)local * 128;
        v0 = b2f(inH[o + lane]);
        v1 = b2f(inH[o + lane + 64]);
    }
    float s = v0 + v1, sq = v0 * v0 + v1 * v1;
    #pragma unroll
    for (int off = 32; off > 0; off >>= 1) { s += __shfl_xor(s, off); sq += __shfl_xor(sq, off); }
    float mean = s * (1.0f / 128.0f);
    float var  = sq * (1.0f / 128.0f) - mean * mean;
    float rstd = rsqrtf(var + 1e-5f);
    float r0 = (v0 - mean) * rstd * g[lane]      + bta[lane];
    float r1 = (v1 - mean) * rstd * g[lane + 64] + bta[lane + 64];
    size_t o = (size_t)local * 128;
    if (mode == 0) {
        unsigned short h0, l0, h1, l1;
        split2(r0, h0, l0); split2(r1, h1, l1);
        outH[o + lane] = h0; outH[o + lane + 64] = h1;
        outL[o + lane] = l0; outL[o + lane + 64] = l1;
    } else {
        outH[o + lane] = bfr(r0); outH[o + lane + 64] = bfr(r1);
    }
}

// ---------------- GEMM: 64x64 tile, planar operands ----------------
// ASPLIT=1: A hi/lo planes, 3-term MFMA (qkv). ASPLIT=0: A bf16, 2-term.
// mode: 0 = bf16 out; 1 = GELU + bf16 out; 2 = bf16 out, bias cols<128 scaled
//       by 1/sqrt(32) (qkv); 3 = fp32 scatter-remap out (fc2 -> y)
template<int ASPLIT>
__global__ __launch_bounds__(256) void gemm_t(
    const unsigned short* __restrict__ Agh, const unsigned short* __restrict__ Agl,
    const unsigned short* __restrict__ Wgh, const unsigned short* __restrict__ Wgl,
    const float* __restrict__ bias,
    float* __restrict__ OutF, unsigned short* __restrict__ OutH,
    int M, int N, int K, int mode, int tbase)
{
    __shared__ __align__(16) unsigned short Ah[64 * STR];
    __shared__ __align__(16) unsigned short Al[(ASPLIT ? 64 : 1) * STR];
    __shared__ __align__(16) unsigned short Wh[64 * STR];
    __shared__ __align__(16) unsigned short Wl[64 * STR];
    int tid = threadIdx.x;
    int wv = tid >> 6, ln = tid & 63;
    int wm = wv & 1, wn = wv >> 1;
    int fm = ln & 15, fq = ln >> 4;
    int m0 = blockIdx.y * 64, n0 = blockIdx.x * 64;
    int sr = tid >> 2, sk = (tid & 3) * 8;
    int arow = m0 + sr; if (arow >= M) arow = M - 1;
    const unsigned short* pAh = Agh + (size_t)arow * K + sk;
    const unsigned short* pAl = ASPLIT ? (Agl + (size_t)arow * K + sk) : nullptr;
    const unsigned short* pWh = Wgh + (size_t)(n0 + sr) * K + sk;
    const unsigned short* pWl = Wgl + (size_t)(n0 + sr) * K + sk;
    int so = sr * STR + sk;

    f4v acc[2][2] = {};
    s8v ra, rl, rwh, rwl;
    #define LOADK(k0) do { \
        ra  = *reinterpret_cast<const s8v*>(pAh + (k0)); \
        if (ASPLIT) rl = *reinterpret_cast<const s8v*>(pAl + (k0)); \
        rwh = *reinterpret_cast<const s8v*>(pWh + (k0)); \
        rwl = *reinterpret_cast<const s8v*>(pWl + (k0)); } while (0)
    LOADK(0);
    for (int k0 = 0; k0 < K; k0 += 32) {
        *reinterpret_cast<s8v*>(&Ah[so]) = ra;
        if (ASPLIT) *reinterpret_cast<s8v*>(&Al[so]) = rl;
        *reinterpret_cast<s8v*>(&Wh[so]) = rwh;
        *reinterpret_cast<s8v*>(&Wl[so]) = rwl;
        __syncthreads();
        if (k0 + 32 < K) LOADK(k0 + 32);        // prefetch next k-step
        s8v fah[2], fal[2], fbh[2], fbl[2];
        #pragma unroll
        for (int t = 0; t < 2; ++t) {
            int ao = (wm * 32 + t * 16 + fm) * STR + fq * 8;
            fah[t] = *reinterpret_cast<const s8v*>(&Ah[ao]);
            if (ASPLIT) fal[t] = *reinterpret_cast<const s8v*>(&Al[ao]);
            int bo = (wn * 32 + t * 16 + fm) * STR + fq * 8;
            fbh[t] = *reinterpret_cast<const s8v*>(&Wh[bo]);
            fbl[t] = *reinterpret_cast<const s8v*>(&Wl[bo]);
        }
        #pragma unroll
        for (int tm = 0; tm < 2; ++tm)
            #pragma unroll
            for (int tn = 0; tn < 2; ++tn) {
                acc[tm][tn] = __builtin_amdgcn_mfma_f32_16x16x32_bf16(fah[tm], fbh[tn], acc[tm][tn], 0, 0, 0);
                acc[tm][tn] = __builtin_amdgcn_mfma_f32_16x16x32_bf16(fah[tm], fbl[tn], acc[tm][tn], 0, 0, 0);
                if (ASPLIT)
                    acc[tm][tn] = __builtin_amdgcn_mfma_f32_16x16x32_bf16(fal[tm], fbh[tn], acc[tm][tn], 0, 0, 0);
            }
        __syncthreads();
    }
    #undef LOADK

    #pragma unroll
    for (int tm = 0; tm < 2; ++tm)
        #pragma unroll
        for (int tn = 0; tn < 2; ++tn) {
            int col = n0 + wn * 32 + tn * 16 + fm;
            float bv = bias[col];
            if (mode == 2 && col < 128) bv *= 0.17677669529663687f;
            #pragma unroll
            for (int r = 0; r < 4; ++r) {
                int m = m0 + wm * 32 + tm * 16 + fq * 4 + r;
                if (m >= M) continue;
                float v = acc[tm][tn][r] + bv;
                if (mode == 1) v = 0.5f * v * (1.0f + erff(v * 0.70710678118654752f));
                if (mode == 3) {
                    int t = tbase + m;
                    int n = t / 49, l = t - n * 49;
                    int b = n >> 6, wh_ = (n >> 3) & 7, ww = n & 7;
                    int i = l / 7, j = l - i * 7;
                    size_t orow = (size_t)((b * 56 + wh_ * 7 + i) * 56 + ww * 7 + j);
                    OutF[orow * N + col] = v;
                } else {
                    OutH[(size_t)m * N + col] = bfr(v);
                }
            }
        }
}

// ---------------- bias table in MFMA C-layout: [4][64 lanes][16 (mt,nt)][4 r] ----------------
__global__ void bias_tab_kernel(const float* __restrict__ pe, float* __restrict__ tab) {
    int t = threadIdx.x;          // 256 = 4 heads x 64 lanes
    int h = t >> 6, ln = t & 63;
    int g = ln >> 4, c = ln & 15;
    for (int mt = 0; mt < 4; ++mt)
        for (int nt = 0; nt < 4; ++nt)
            for (int r = 0; r < 4; ++r) {
                int l1 = mt * 16 + g * 4 + r, l2 = nt * 16 + c;
                float b = 0.f;
                if (l1 < 49 && l2 < 49) {
                    int i1 = l1 / 7, j1 = l1 % 7, i2 = l2 / 7, j2 = l2 % 7;
                    b = pe[h * 169 + (i1 - i2 + 6) * 13 + (j1 - j2 + 6)];
                }
                tab[((h * 64 + ln) * 16 + mt * 4 + nt) * 4 + r] = b;
            }
}

// ---------------- MFMA attention: one block per window, wave = head ----------------
// Input: qkv bf16 [wpc,49,384] (Q pre-scaled). Output: bf16 plane [wpc,49,128].
// Per-head LDS (shorts): Q[64*40]  K[64*40]  V^T[32*72]; P[64*72] aliases Q+K.
#define HB 7424   // per-head shorts: 2560 + 2560 + 2304
__global__ __launch_bounds__(256) void attn_mfma(
    const unsigned short* __restrict__ qkv,
    const float* __restrict__ btab,
    unsigned short* __restrict__ oH)
{
    __shared__ __align__(16) unsigned short lds[4 * HB];
    int tid = threadIdx.x;
    int win = blockIdx.x;
    const unsigned short* src = qkv + (size_t)win * 49 * 384;

    // zero V^T pad cols l2=49..63 (4 heads x 32 d x 15)
    for (int i = tid; i < 1920; i += 256) {
        int hh = i / 480, rem = i % 480, d = rem / 15, l2 = 49 + rem % 15;
        lds[hh * HB + 5120 + d * 72 + l2] = 0;
    }
    // stage QKV bf16 -> LDS (Q already scaled)
    for (int idx = tid; idx < 2352; idx += 256) {
        int l2 = idx / 48, c8 = idx - l2 * 48;
        int d8 = c8 * 8;
        s8v v8 = *reinterpret_cast<const s8v*>(src + (size_t)l2 * 384 + d8);
        int sec = d8 >> 7, dd = d8 & 127, hh = dd >> 5, kk = dd & 31;
        int base = hh * HB;
        if (sec <= 1) {
            *reinterpret_cast<s8v*>(&lds[base + sec * 2560 + l2 * 40 + kk]) = v8;
        } else {
            #pragma unroll
            for (int i = 0; i < 8; ++i)
                lds[base + 5120 + (kk + i) * 72 + l2] = (unsigned short)v8[i];
        }
    }
    __syncthreads();

    int h = tid >> 6, ln = tid & 63;
    int fm = ln & 15, fq = ln >> 4;
    int base = h * HB;

    // S = Q @ K^T  (+ bias from table)
    s8v Qf[4], Kf[4];
    #pragma unroll
    for (int t = 0; t < 4; ++t) {
        Qf[t] = *reinterpret_cast<const s8v*>(&lds[base + (t * 16 + fm) * 40 + fq * 8]);
        Kf[t] = *reinterpret_cast<const s8v*>(&lds[base + 2560 + (t * 16 + fm) * 40 + fq * 8]);
    }
    f4v S[4][4] = {};
    #pragma unroll
    for (int mt = 0; mt < 4; ++mt)
        #pragma unroll
        for (int nt = 0; nt < 4; ++nt)
            S[mt][nt] = __builtin_amdgcn_mfma_f32_16x16x32_bf16(Qf[mt], Kf[nt], S[mt][nt], 0, 0, 0);
    #pragma unroll
    for (int mt = 0; mt < 4; ++mt)
        #pragma unroll
        for (int nt = 0; nt < 4; ++nt)
            S[mt][nt] += *reinterpret_cast<const f4v*>(&btab[((h * 64 + ln) * 16 + mt * 4 + nt) * 4]);

    // in-register softmax per row (rows live in 16-lane shuffle groups); P -> LDS (aliases Q+K)
    float rcp[16];
    #pragma unroll
    for (int mt = 0; mt < 4; ++mt) {
        #pragma unroll
        for (int r = 0; r < 4; ++r) {
            float v0 = S[mt][0][r], v1 = S[mt][1][r], v2 = S[mt][2][r], v3 = S[mt][3][r];
            if (fm != 0) v3 = -1e30f;                       // cols 49..63 masked
            float mx = fmaxf(fmaxf(v0, v1), fmaxf(v2, v3));
            #pragma unroll
            for (int off = 1; off < 16; off <<= 1) mx = fmaxf(mx, __shfl_xor(mx, off));
            float e0 = __expf(v0 - mx), e1 = __expf(v1 - mx);
            float e2 = __expf(v2 - mx), e3 = __expf(v3 - mx); // masked -> 0
            float sm = e0 + e1 + e2 + e3;
            #pragma unroll
            for (int off = 1; off < 16; off <<= 1) sm += __shfl_xor(sm, off);
            rcp[mt * 4 + r] = 1.0f / sm;
            int row = mt * 16 + fq * 4 + r;
            lds[base + row * 72 + 0 * 16 + fm]  = bfr(e0);
            lds[base + row * 72 + 1 * 16 + fm]  = bfr(e1);
            lds[base + row * 72 + 2 * 16 + fm]  = bfr(e2);
            lds[base + row * 72 + 3 * 16 + fm]  = bfr(e3);
        }
    }

    // O = P @ V   (V^T staged as B operand; k = l2, two k-steps)
    f4v O[4][2] = {};
    #pragma unroll
    for (int kt = 0; kt < 2; ++kt) {
        s8v Pf[4], Vf[2];
        #pragma unroll
        for (int mt = 0; mt < 4; ++mt)
            Pf[mt] = *reinterpret_cast<const s8v*>(&lds[base + (mt * 16 + fm) * 72 + kt * 32 + fq * 8]);
        #pragma unroll
        for (int nt = 0; nt < 2; ++nt)
            Vf[nt] = *reinterpret_cast<const s8v*>(&lds[base + 5120 + (nt * 16 + fm) * 72 + kt * 32 + fq * 8]);
        #pragma unroll
        for (int mt = 0; mt < 4; ++mt)
            #pragma unroll
            for (int nt = 0; nt < 2; ++nt)
                O[mt][nt] = __builtin_amdgcn_mfma_f32_16x16x32_bf16(Pf[mt], Vf[nt], O[mt][nt], 0, 0, 0);
    }

    size_t ob = (size_t)win * 49 * 128 + h * 32;
    #pragma unroll
    for (int mt = 0; mt < 4; ++mt)
        #pragma unroll
        for (int r = 0; r < 4; ++r) {
            int row = mt * 16 + fq * 4 + r;
            if (row < 49) {
                float sc = rcp[mt * 4 + r];
                #pragma unroll
                for (int nt = 0; nt < 2; ++nt)
                    oH[ob + (size_t)row * 128 + nt * 16 + fm] = bfr(O[mt][nt][r] * sc);
            }
        }
}

extern "C" void kernel_launch(void* const* d_in, const int* in_sizes, int n_in,
                              void* d_out, int out_size, void* d_ws, size_t ws_size,
                              hipStream_t stream) {
    const float* x    = (const float*)d_in[0];
    const float* n1g  = (const float*)d_in[1];
    const float* n1b  = (const float*)d_in[2];
    const float* qkvw = (const float*)d_in[3];
    const float* qkvb = (const float*)d_in[4];
    const float* outw = (const float*)d_in[5];
    const float* outb = (const float*)d_in[6];
    const float* pe   = (const float*)d_in[7];
    const float* n2g  = (const float*)d_in[8];
    const float* n2b  = (const float*)d_in[9];
    const float* w1   = (const float*)d_in[10];
    const float* b1   = (const float*)d_in[11];
    const float* w2   = (const float*)d_in[12];
    const float* b2   = (const float*)d_in[13];
    float* y = (float*)d_out;

    // fixed overhead: 64 KB btab + 768 KB weight planes = 851968 B
    size_t wpc = NWIN;
    while (wpc > 8 && 851968 + wpc * 49 * 1536 > ws_size) wpc >>= 1;
    const int nchunks = (int)(NWIN / wpc);
    const size_t rows = wpc * 49;

    char* ws = (char*)d_ws;
    float* btab = (float*)ws;                                    // 64 KB
    unsigned short* wpl = (unsigned short*)(ws + 65536);         // 786432 B of planes
    unsigned short* bufAh = (unsigned short*)(ws + 851968);      // rows*128 shorts
    unsigned short* bufAl = bufAh + rows * 128;                  // rows*128 shorts (LN1 lo only)
    unsigned short* bufBh = bufAl + rows * 128;                  // rows*512 shorts
    const int gy = (int)((rows + 63) / 64);

    presplit_kernel<<<768, 256, 0, stream>>>(qkvw, outw, w1, w2, wpl);
    bias_tab_kernel<<<1, 256, 0, stream>>>(pe, btab);

    for (int c = 0; c < nchunks; ++c) {
        int tbase = (int)(c * wpc * 49);
        // LN1: fp32 gather -> hi/lo planes
        ln_kernel<<<(int)(rows / 4), 256, 0, stream>>>(
            x, nullptr, n1g, n1b, bufAh, bufAl, 0, tbase);
        // QKV: A hi/lo (3-term) -> bf16 [rows,384], Q pre-scaled
        gemm_t<1><<<dim3(6, gy), 256, 0, stream>>>(
            bufAh, bufAl, wpl, wpl + 49152, qkvb,
            nullptr, bufBh, (int)rows, 384, 128, 2, 0);
        // attention -> bf16 [rows,128]
        attn_mfma<<<(int)wpc, 256, 0, stream>>>(bufBh, btab, bufAh);
        // proj: A bf16 (2-term) -> bf16 [rows,128]
        gemm_t<0><<<dim3(2, gy), 256, 0, stream>>>(
            bufAh, nullptr, wpl + 98304, wpl + 114688, outb,
            nullptr, bufBh, (int)rows, 128, 128, 0, 0);
        // LN2: bf16 -> bf16
        ln_kernel<<<(int)(rows / 4), 256, 0, stream>>>(
            nullptr, bufBh, n2g, n2b, bufAh, nullptr, 1, 0);
        // fc1 + GELU: A bf16 -> bf16 hidden [rows,512]
        gemm_t<0><<<dim3(8, gy), 256, 0, stream>>>(
            bufAh, nullptr, wpl + 131072, wpl + 196608, b1,
            nullptr, bufBh, (int)rows, 512, 128, 1, 0);
        // fc2: A bf16 -> fp32 scatter to y
        gemm_t<0><<<dim3(2, gy), 256, 0, stream>>>(
            bufBh, nullptr, wpl + 262144, wpl + 327680, b2,
            y, nullptr, (int)rows, 128, 512, 3, tbase);
    }
}